// Round 5
// baseline (3101.881 us; speedup 1.0000x reference)
//
#include <hip/hip_runtime.h>
#include <cstdint>
#include <cstddef>

typedef _Float16 half8 __attribute__((ext_vector_type(8)));
typedef float f32x4 __attribute__((ext_vector_type(4)));

#define S_LEN 2048
#define HDIM  256
#define BATCH 64
#define LROW  264   // LDS row stride in f16 (dword stride 132 ≡ 4 mod 32)
#define NSBLK 32    // 2048 steps / 64-step flag blocks

__device__ __forceinline__ float tanh_fast(float x) {
    // tanh(x) = 1 - 2/(e^{2x}+1)
    float e = exp2f(x * 2.8853900817779268f);
    return 1.0f - 2.0f / (e + 1.0f);
}

// ---------------------------------------------------------------------------
// Fused kernel. Blocks 0..3: recurrence consumers (one per 16-batch group,
// 4 waves x 64 output cols). Blocks 4..8195: xp producers (64x64 tile each),
// dispatched k-major (all batches' step-block k before k+1). Producer->
// consumer handoff via device-scope counters in d_ws: cnt[wg][k] counts
// finished tiles (target 64 = 16 batches x 4 col-tiles). Consumers spin only
// at 64-step boundaries, 2 steps ahead of consumption.
// ---------------------------------------------------------------------------
__global__ void __launch_bounds__(256, 2) rnn_fused(
    const float* __restrict__ x, const float* __restrict__ Wxh,
    const float* __restrict__ bxh, const float* __restrict__ Whh,
    const float* __restrict__ bhh, float* __restrict__ out,
    int* __restrict__ cnt) {

    if (blockIdx.x >= 4) {
        // ================= producer: one 64x64 xp tile =================
        __shared__ float As[32][68];
        __shared__ float Bs[32][68];
        const int id = blockIdx.x - 4;
        const int kb = id >> 8;          // step-block 0..31 (outermost in dispatch)
        const int rr = id & 255;
        const int b  = rr >> 2;          // batch 0..63
        const int nt = rr & 3;           // col tile 0..3
        const size_t m0 = (size_t)b * S_LEN + (size_t)kb * 64;
        const int n0 = nt * 64;

        const int tid = threadIdx.x;
        const int tx = tid & 15;
        const int ty = tid >> 4;
        const int r = tid >> 3;
        const int c = (tid & 7) * 4;

        float bj[4];
#pragma unroll
        for (int j = 0; j < 4; j++) bj[j] = bxh[n0 + tx * 4 + j];

        float acc[4][4] = {};

        for (int k0 = 0; k0 < 256; k0 += 32) {
            float4 a0 = *(const float4*)&x[(m0 + r) * 256 + k0 + c];
            float4 a1 = *(const float4*)&x[(m0 + r + 32) * 256 + k0 + c];
            float4 b0 = *(const float4*)&Wxh[(size_t)(n0 + r) * 256 + k0 + c];
            float4 b1 = *(const float4*)&Wxh[(size_t)(n0 + r + 32) * 256 + k0 + c];

            __syncthreads();
            As[c + 0][r] = a0.x; As[c + 1][r] = a0.y; As[c + 2][r] = a0.z; As[c + 3][r] = a0.w;
            As[c + 0][r + 32] = a1.x; As[c + 1][r + 32] = a1.y; As[c + 2][r + 32] = a1.z; As[c + 3][r + 32] = a1.w;
            Bs[c + 0][r] = b0.x; Bs[c + 1][r] = b0.y; Bs[c + 2][r] = b0.z; Bs[c + 3][r] = b0.w;
            Bs[c + 0][r + 32] = b1.x; Bs[c + 1][r + 32] = b1.y; Bs[c + 2][r + 32] = b1.z; Bs[c + 3][r + 32] = b1.w;
            __syncthreads();

#pragma unroll
            for (int kk = 0; kk < 32; kk++) {
                float4 av = *(const float4*)&As[kk][ty * 4];
                float4 bv = *(const float4*)&Bs[kk][tx * 4];
                float aa[4] = {av.x, av.y, av.z, av.w};
                float bb[4] = {bv.x, bv.y, bv.z, bv.w};
#pragma unroll
                for (int i = 0; i < 4; i++)
#pragma unroll
                    for (int j = 0; j < 4; j++)
                        acc[i][j] = fmaf(aa[i], bb[j], acc[i][j]);
            }
        }

#pragma unroll
        for (int i = 0; i < 4; i++) {
            float4 o;
            o.x = acc[i][0] + bj[0];
            o.y = acc[i][1] + bj[1];
            o.z = acc[i][2] + bj[2];
            o.w = acc[i][3] + bj[3];
            *(float4*)&out[(m0 + ty * 4 + i) * 256 + n0 + tx * 4] = o;
        }

        __syncthreads();  // all waves' stores drained (vmcnt(0) at barrier)
        if (threadIdx.x == 0) {
            __threadfence();  // device-scope: flush to MALL for cross-XCD readers
            atomicAdd(&cnt[(b >> 4) * NSBLK + kb], 1);
        }
        return;
    }

    // ================= consumer: recurrence for 16 batches =================
    const int wg = blockIdx.x;      // batch group 0..3
    const int t = threadIdx.x;      // 256 threads = 4 waves
    const int w = t >> 6;           // wave 0..3, owns cols [w*64, w*64+64)
    const int l = t & 63;
    const int c = l & 15;           // A-row (batch within tile) / col offset
    const int g = l >> 4;           // k-group 0..3
    const int colbase = w * 64 + c; // col of n-tile 0; tile nt adds nt*16

    __shared__ _Float16 hls[2][16][LROW];

    // ---- one-time: W_hh B-fragments (4 n-tiles x 8 k-frags) ----
    half8 wf[4][8];
    float bv[4];
#pragma unroll
    for (int nt = 0; nt < 4; nt++) {
        const float* wr = Whh + (size_t)(colbase + nt * 16) * HDIM;
#pragma unroll
        for (int kt = 0; kt < 8; kt++) {
            float4 u = *(const float4*)&wr[kt * 32 + 8 * g];
            float4 v = *(const float4*)&wr[kt * 32 + 8 * g + 4];
            half8 f;
            f[0] = (_Float16)u.x; f[1] = (_Float16)u.y;
            f[2] = (_Float16)u.z; f[3] = (_Float16)u.w;
            f[4] = (_Float16)v.x; f[5] = (_Float16)v.y;
            f[6] = (_Float16)v.z; f[7] = (_Float16)v.w;
            wf[nt][kt] = f;
        }
        bv[nt] = bhh[colbase + nt * 16];
    }

    // ---- zero h_0 (both buffers) ----
    for (int i = t; i < 2 * 16 * LROW; i += 256) (&hls[0][0][0])[i] = (_Float16)0.f;

    // ---- global byte offsets (32-bit) over SGPR base ----
    const char* ob = (const char*)out;
    uint32_t boffA[4], boffB[4];
#pragma unroll
    for (int r = 0; r < 4; r++) {
        boffA[r] = (uint32_t)((((size_t)(wg * 16 + 4 * g + r) * S_LEN * HDIM) + colbase) * 4u);
        boffB[r] = boffA[r] + HDIM * 4;  // next step's row
    }
    float* hl = out + (size_t)BATCH * S_LEN * HDIM;
    int* mycnt = cnt + wg * NSBLK;

    // ---- wait for step-block 0, then prologue xp s=0 / s=1 ----
    while (__hip_atomic_load(mycnt, __ATOMIC_ACQUIRE, __HIP_MEMORY_SCOPE_AGENT) < 64)
        __builtin_amdgcn_s_sleep(16);

    f32x4 xA[4], xB[4];
#pragma unroll
    for (int nt = 0; nt < 4; nt++)
#pragma unroll
        for (int r = 0; r < 4; r++) {
            xA[nt][r] = *(const float*)(ob + boffA[r] + nt * 64);
            xB[nt][r] = *(const float*)(ob + boffB[r] + nt * 64);
        }

    const _Float16* rdA = &hls[0][c][8 * g];
    const _Float16* rdB = &hls[1][c][8 * g];
    _Float16* wrA = &hls[1][4 * g][colbase];
    _Float16* wrB = &hls[0][4 * g][colbase];

    __syncthreads();

    auto phase = [&](int s, f32x4 (&xq)[4], uint32_t (&boff)[4],
                     const _Float16* rb, _Float16* wb) {
        // A-fragments (shared across the wave's 4 n-tiles)
        half8 af[8];
#pragma unroll
        for (int kt = 0; kt < 8; kt++)
            af[kt] = *(const half8*)(rb + kt * 32);

        // seed accumulators with xp + bias
        f32x4 a[4];
#pragma unroll
        for (int nt = 0; nt < 4; nt++)
#pragma unroll
            for (int r = 0; r < 4; r++)
                a[nt][r] = xq[nt][r] + bv[nt];

        // prefetch xp for s+2 (flag-gated only at 64-step boundaries)
        if (s + 2 < S_LEN) {
            if (((s + 2) & 63) == 0) {
                int kb2 = (s + 2) >> 6;
                while (__hip_atomic_load(mycnt + kb2, __ATOMIC_ACQUIRE,
                                         __HIP_MEMORY_SCOPE_AGENT) < 64)
                    __builtin_amdgcn_s_sleep(16);
            }
#pragma unroll
            for (int nt = 0; nt < 4; nt++)
#pragma unroll
                for (int r = 0; r < 4; r++)
                    xq[nt][r] = *(const float*)(ob + boff[r] + nt * 64 + 2048);
        }

        // MFMA: kt outer, 4 independent n-tile chains inner
#pragma unroll
        for (int kt = 0; kt < 8; kt++)
#pragma unroll
            for (int nt = 0; nt < 4; nt++)
                a[nt] = __builtin_amdgcn_mfma_f32_16x16x32_f16(af[kt], wf[nt][kt], a[nt], 0, 0, 0);

        // epilogue: tanh, h_seq store, f16 h post
        float vs[4][4];
#pragma unroll
        for (int nt = 0; nt < 4; nt++)
#pragma unroll
            for (int r = 0; r < 4; r++) {
                float v = tanh_fast(a[nt][r]);
                vs[nt][r] = v;
                *(float*)(ob + boff[r] + nt * 64) = v;
                wb[r * LROW + nt * 16] = (_Float16)v;
            }
        if (s == S_LEN - 1) {
#pragma unroll
            for (int nt = 0; nt < 4; nt++)
#pragma unroll
                for (int r = 0; r < 4; r++)
                    hl[(wg * 16 + 4 * g + r) * HDIM + colbase + nt * 16] = vs[nt][r];
        }
#pragma unroll
        for (int r = 0; r < 4; r++) boff[r] += 2 * HDIM * 4;
        __syncthreads();
    };

    for (int s = 0; s < S_LEN; s += 2) {
        phase(s, xA, boffA, rdA, wrA);
        phase(s + 1, xB, boffB, rdB, wrB);
    }
}

extern "C" void kernel_launch(void* const* d_in, const int* in_sizes, int n_in,
                              void* d_out, int out_size, void* d_ws, size_t ws_size,
                              hipStream_t stream) {
    const float* x   = (const float*)d_in[0];
    const float* Wxh = (const float*)d_in[1];
    const float* bxh = (const float*)d_in[2];
    const float* Whh = (const float*)d_in[3];
    const float* bhh = (const float*)d_in[4];
    float* out = (float*)d_out;
    int* cnt = (int*)d_ws;

    hipMemsetAsync(cnt, 0, 4 * NSBLK * sizeof(int), stream);
    rnn_fused<<<4 + 64 * NSBLK * 4, 256, 0, stream>>>(x, Wxh, bxh, Whh, bhh, out, cnt);
}

// Round 7
// 2889.504 us; speedup vs baseline: 1.0735x; 1.0735x over previous
//
#include <hip/hip_runtime.h>
#include <cstdint>
#include <cstddef>

typedef _Float16 half8 __attribute__((ext_vector_type(8)));
typedef __fp16 fp16x2 __attribute__((ext_vector_type(2)));
typedef float f32x4 __attribute__((ext_vector_type(4)));

#define S_LEN 2048
#define HDIM  256
#define BATCH 64
#define LROW  264   // LDS row stride in f16 (dword stride 132 ≡ 4 mod 32 -> conflict-free b128 reads)

__device__ __forceinline__ float tanh_fast(float x) {
    // tanh(x) = 1 - 2/(e^{2x}+1)
    float e = exp2f(x * 2.8853900817779268f);
    return 1.0f - 2.0f / (e + 1.0f);
}

__device__ __forceinline__ uint32_t pk_f16(float a, float b) {
#if __has_builtin(__builtin_amdgcn_cvt_pkrtz)
    fp16x2 h = __builtin_amdgcn_cvt_pkrtz(a, b);
    return __builtin_bit_cast(uint32_t, h);
#else
    union { _Float16 h[2]; uint32_t u; } v;
    v.h[0] = (_Float16)a; v.h[1] = (_Float16)b;
    return v.u;
#endif
}

// ---------------------------------------------------------------------------
// Kernel A: xp[m, h] = sum_i x[m, i] * Wxh[h, i] + bxh[h]   (unchanged)
// ---------------------------------------------------------------------------
__global__ void __launch_bounds__(256) xp_gemm(
    const float* __restrict__ x, const float* __restrict__ Wxh,
    const float* __restrict__ bxh, float* __restrict__ out) {
    __shared__ float As[32][68];
    __shared__ float Bs[32][68];

    const int tid = threadIdx.x;
    const int tx = tid & 15;
    const int ty = tid >> 4;
    const size_t m0 = (size_t)blockIdx.x * 64;
    const int n0 = blockIdx.y * 64;

    const int r = tid >> 3;
    const int c = (tid & 7) * 4;

    float bj[4];
#pragma unroll
    for (int j = 0; j < 4; j++) bj[j] = bxh[n0 + tx * 4 + j];

    float acc[4][4] = {};

    for (int k0 = 0; k0 < 256; k0 += 32) {
        float4 a0 = *(const float4*)&x[(m0 + r) * 256 + k0 + c];
        float4 a1 = *(const float4*)&x[(m0 + r + 32) * 256 + k0 + c];
        float4 b0 = *(const float4*)&Wxh[(size_t)(n0 + r) * 256 + k0 + c];
        float4 b1 = *(const float4*)&Wxh[(size_t)(n0 + r + 32) * 256 + k0 + c];

        __syncthreads();
        As[c + 0][r] = a0.x; As[c + 1][r] = a0.y; As[c + 2][r] = a0.z; As[c + 3][r] = a0.w;
        As[c + 0][r + 32] = a1.x; As[c + 1][r + 32] = a1.y; As[c + 2][r + 32] = a1.z; As[c + 3][r + 32] = a1.w;
        Bs[c + 0][r] = b0.x; Bs[c + 1][r] = b0.y; Bs[c + 2][r] = b0.z; Bs[c + 3][r] = b0.w;
        Bs[c + 0][r + 32] = b1.x; Bs[c + 1][r + 32] = b1.y; Bs[c + 2][r + 32] = b1.z; Bs[c + 3][r + 32] = b1.w;
        __syncthreads();

#pragma unroll
        for (int kk = 0; kk < 32; kk++) {
            float4 av = *(const float4*)&As[kk][ty * 4];
            float4 bv = *(const float4*)&Bs[kk][tx * 4];
            float aa[4] = {av.x, av.y, av.z, av.w};
            float bb[4] = {bv.x, bv.y, bv.z, bv.w};
#pragma unroll
            for (int i = 0; i < 4; i++)
#pragma unroll
                for (int j = 0; j < 4; j++)
                    acc[i][j] = fmaf(aa[i], bb[j], acc[i][j]);
        }
    }

#pragma unroll
    for (int i = 0; i < 4; i++) {
        float4 o;
        o.x = acc[i][0] + bj[0];
        o.y = acc[i][1] + bj[1];
        o.z = acc[i][2] + bj[2];
        o.w = acc[i][3] + bj[3];
        *(float4*)&out[(m0 + ty * 4 + i) * 256 + n0 + tx * 4] = o;
    }
}

// ---------------------------------------------------------------------------
// Kernel B: MFMA recurrence, swapped orientation D[col][batch] = W·h^T.
// 4 WGs (one per 16-batch group) x 256 threads (4 waves, 1/SIMD, no VGPR cap).
// Wave w owns output h-cols [64w, 64w+64) as m-tiles mtl=0..3.
//   A (static, VGPR): wf[mtl][kt] elem j = Whh[64w+16mtl+c][32kt+8g+j]
//   B (LDS):          af[kt]      elem j = h[batch c][32kt+8g+j]  (b128, conflict-free)
//   D: lane (c,g) reg r = h_next[batch c][64w+16mtl+4g+r]  -> batch-major,
//      4-consecutive-col groups => dwordx4 global I/O, ds_write_b64 LDS posts.
// One barrier/step; xp prefetched 2 steps ahead (2-phase A/B reg sets).
// ---------------------------------------------------------------------------
__global__ void __launch_bounds__(256, 1) rnn_mfma(
    const float* __restrict__ Whh, const float* __restrict__ bhh,
    float* __restrict__ out) {
    const int wg = blockIdx.x;      // batch group 0..3
    const int t = threadIdx.x;
    const int w = t >> 6;           // wave 0..3
    const int l = t & 63;
    const int c = l & 15;           // batch within group (N-index of D)
    const int g = l >> 4;           // k-group 0..3

    __shared__ _Float16 hls[2][16][LROW];

    // ---- one-time: W_hh A-fragments (4 m-tiles x 8 k-frags) ----
    half8 wf[4][8];
#pragma unroll
    for (int mtl = 0; mtl < 4; mtl++) {
        const float* wr = Whh + (size_t)(64 * w + 16 * mtl + c) * HDIM;
#pragma unroll
        for (int kt = 0; kt < 8; kt++) {
            float4 u = *(const float4*)&wr[32 * kt + 8 * g];
            float4 v = *(const float4*)&wr[32 * kt + 8 * g + 4];
            half8 f;
            f[0] = (_Float16)u.x; f[1] = (_Float16)u.y;
            f[2] = (_Float16)u.z; f[3] = (_Float16)u.w;
            f[4] = (_Float16)v.x; f[5] = (_Float16)v.y;
            f[6] = (_Float16)v.z; f[7] = (_Float16)v.w;
            wf[mtl][kt] = f;
        }
    }
    // bias for this lane's 16 output cols
    f32x4 bvv[4];
#pragma unroll
    for (int mtl = 0; mtl < 4; mtl++) {
        float4 bb = *(const float4*)&bhh[64 * w + 16 * mtl + 4 * g];
        bvv[mtl][0] = bb.x; bvv[mtl][1] = bb.y; bvv[mtl][2] = bb.z; bvv[mtl][3] = bb.w;
    }

    // ---- zero h_0 (both buffers) ----
    for (int i = t; i < 2 * 16 * LROW; i += 256) (&hls[0][0][0])[i] = (_Float16)0.f;

    // ---- global addressing: lane's batch row = wg*16 + c ----
    const char* ob = (const char*)out;
    uint32_t boffA = (uint32_t)((((size_t)(wg * 16 + c) * S_LEN * HDIM) + 64 * w + 4 * g) * 4u);
    uint32_t boffB = boffA + HDIM * 4;
    float* hl = out + (size_t)BATCH * S_LEN * HDIM;

    // ---- prologue: xp for s=0 / s=1 ----
    f32x4 xA[4], xB[4];
#pragma unroll
    for (int mtl = 0; mtl < 4; mtl++) {
        xA[mtl] = *(const f32x4*)(ob + boffA + mtl * 64);
        xB[mtl] = *(const f32x4*)(ob + boffB + mtl * 64);
    }

    // ---- LDS base pointers ----
    const _Float16* rdA = &hls[0][c][8 * g];
    const _Float16* rdB = &hls[1][c][8 * g];
    _Float16* wrA = &hls[1][c][64 * w + 4 * g];
    _Float16* wrB = &hls[0][c][64 * w + 4 * g];

    __syncthreads();

    auto phase = [&](int s, f32x4 (&xq)[4], uint32_t& boff,
                     const _Float16* rb, _Float16* wb) {
        // B-fragments: h rows from LDS (16B contiguous, conflict-free)
        half8 af[8];
#pragma unroll
        for (int kt = 0; kt < 8; kt++)
            af[kt] = *(const half8*)(rb + 32 * kt);

        // seed accumulators with xp + bias
        f32x4 a[4];
#pragma unroll
        for (int mtl = 0; mtl < 4; mtl++)
            a[mtl] = xq[mtl] + bvv[mtl];

        // prefetch xp for s+2
        if (s + 2 < S_LEN) {
#pragma unroll
            for (int mtl = 0; mtl < 4; mtl++)
                xq[mtl] = *(const f32x4*)(ob + boff + mtl * 64 + 2048);
        }

        // MFMA: A = weights (static), B = h fragments
#pragma unroll
        for (int kt = 0; kt < 8; kt++)
#pragma unroll
            for (int mtl = 0; mtl < 4; mtl++)
                a[mtl] = __builtin_amdgcn_mfma_f32_16x16x32_f16(wf[mtl][kt], af[kt], a[mtl], 0, 0, 0);

        // epilogue: tanh -> dwordx4 h_seq store + b64 LDS post
#pragma unroll
        for (int mtl = 0; mtl < 4; mtl++) {
            f32x4 v;
            v[0] = tanh_fast(a[mtl][0]);
            v[1] = tanh_fast(a[mtl][1]);
            v[2] = tanh_fast(a[mtl][2]);
            v[3] = tanh_fast(a[mtl][3]);
            *(f32x4*)(ob + boff + mtl * 64) = v;
            uint2 pk;
            pk.x = pk_f16(v[0], v[1]);
            pk.y = pk_f16(v[2], v[3]);
            *(uint2*)(wb + 16 * mtl) = pk;
            if (s == S_LEN - 1) {
                *(f32x4*)&hl[(size_t)(wg * 16 + c) * HDIM + 64 * w + 16 * mtl + 4 * g] = v;
            }
        }
        boff += 2 * HDIM * 4;
        __syncthreads();
    };

    for (int s = 0; s < S_LEN; s += 2) {
        phase(s, xA, boffA, rdA, wrA);
        phase(s + 1, xB, boffB, rdB, wrB);
    }
}

extern "C" void kernel_launch(void* const* d_in, const int* in_sizes, int n_in,
                              void* d_out, int out_size, void* d_ws, size_t ws_size,
                              hipStream_t stream) {
    const float* x   = (const float*)d_in[0];
    const float* Wxh = (const float*)d_in[1];
    const float* bxh = (const float*)d_in[2];
    const float* Whh = (const float*)d_in[3];
    const float* bhh = (const float*)d_in[4];
    float* out = (float*)d_out;

    dim3 gridA(131072 / 64, 256 / 64);  // (2048, 4)
    xp_gemm<<<gridA, 256, 0, stream>>>(x, Wxh, bxh, out);
    rnn_mfma<<<4, 256, 0, stream>>>(Whh, bhh, out);
}

// Round 8
// 2379.507 us; speedup vs baseline: 1.3036x; 1.2143x over previous
//
#include <hip/hip_runtime.h>
#include <cstdint>
#include <cstddef>

typedef _Float16 half8 __attribute__((ext_vector_type(8)));
typedef __fp16 fp16x2 __attribute__((ext_vector_type(2)));
typedef float f32x4 __attribute__((ext_vector_type(4)));

#define S_LEN 2048
#define HDIM  256
#define BATCH 64
#define LROW  264   // LDS row stride in f16 (dword stride 132 ≡ 4 mod 32)

__device__ __forceinline__ float tanh_fast(float x) {
    // tanh(x) = 1 - 2/(e^{2x}+1)
    float e = exp2f(x * 2.8853900817779268f);
    return 1.0f - 2.0f / (e + 1.0f);
}

__device__ __forceinline__ uint32_t pk_f16(float a, float b) {
#if __has_builtin(__builtin_amdgcn_cvt_pkrtz)
    fp16x2 h = __builtin_amdgcn_cvt_pkrtz(a, b);
    return __builtin_bit_cast(uint32_t, h);
#else
    union { _Float16 h[2]; uint32_t u; } v;
    v.h[0] = (_Float16)a; v.h[1] = (_Float16)b;
    return v.u;
#endif
}

// ---------------------------------------------------------------------------
// Kernel A: xp[m, h] = sum_i x[m, i] * Wxh[h, i] + bxh[h]   (unchanged)
// ---------------------------------------------------------------------------
__global__ void __launch_bounds__(256) xp_gemm(
    const float* __restrict__ x, const float* __restrict__ Wxh,
    const float* __restrict__ bxh, float* __restrict__ out) {
    __shared__ float As[32][68];
    __shared__ float Bs[32][68];

    const int tid = threadIdx.x;
    const int tx = tid & 15;
    const int ty = tid >> 4;
    const size_t m0 = (size_t)blockIdx.x * 64;
    const int n0 = blockIdx.y * 64;

    const int r = tid >> 3;
    const int c = (tid & 7) * 4;

    float bj[4];
#pragma unroll
    for (int j = 0; j < 4; j++) bj[j] = bxh[n0 + tx * 4 + j];

    float acc[4][4] = {};

    for (int k0 = 0; k0 < 256; k0 += 32) {
        float4 a0 = *(const float4*)&x[(m0 + r) * 256 + k0 + c];
        float4 a1 = *(const float4*)&x[(m0 + r + 32) * 256 + k0 + c];
        float4 b0 = *(const float4*)&Wxh[(size_t)(n0 + r) * 256 + k0 + c];
        float4 b1 = *(const float4*)&Wxh[(size_t)(n0 + r + 32) * 256 + k0 + c];

        __syncthreads();
        As[c + 0][r] = a0.x; As[c + 1][r] = a0.y; As[c + 2][r] = a0.z; As[c + 3][r] = a0.w;
        As[c + 0][r + 32] = a1.x; As[c + 1][r + 32] = a1.y; As[c + 2][r + 32] = a1.z; As[c + 3][r + 32] = a1.w;
        Bs[c + 0][r] = b0.x; Bs[c + 1][r] = b0.y; Bs[c + 2][r] = b0.z; Bs[c + 3][r] = b0.w;
        Bs[c + 0][r + 32] = b1.x; Bs[c + 1][r + 32] = b1.y; Bs[c + 2][r + 32] = b1.z; Bs[c + 3][r + 32] = b1.w;
        __syncthreads();

#pragma unroll
        for (int kk = 0; kk < 32; kk++) {
            float4 av = *(const float4*)&As[kk][ty * 4];
            float4 bv = *(const float4*)&Bs[kk][tx * 4];
            float aa[4] = {av.x, av.y, av.z, av.w};
            float bb[4] = {bv.x, bv.y, bv.z, bv.w};
#pragma unroll
            for (int i = 0; i < 4; i++)
#pragma unroll
                for (int j = 0; j < 4; j++)
                    acc[i][j] = fmaf(aa[i], bb[j], acc[i][j]);
        }
    }

#pragma unroll
    for (int i = 0; i < 4; i++) {
        float4 o;
        o.x = acc[i][0] + bj[0];
        o.y = acc[i][1] + bj[1];
        o.z = acc[i][2] + bj[2];
        o.w = acc[i][3] + bj[3];
        *(float4*)&out[(m0 + ty * 4 + i) * 256 + n0 + tx * 4] = o;
    }
}

// ---------------------------------------------------------------------------
// Kernel B: MFMA recurrence, swapped orientation D[col][batch] = W·h^T.
// 4 WGs (one per 16-batch group) x 512 threads = 8 waves (2/SIMD for TLP).
// Wave w owns output h-cols [32w, 32w+32) as m-tiles mtl=0..1.
//   A (static, VGPR): wf[mtl][kt] elem j = Whh[32w+16mtl+c][32kt+8g+j]  (64 VGPR)
//   B (LDS):          af[kt]      elem j = h[batch c][32kt+8g+j]  (b128 reads)
//   D: lane (c,g) reg r = h_next[batch c][32w+16mtl+4g+r] -> batch-major,
//      4-consecutive-col groups => dwordx4 global I/O, b64 LDS posts.
// Total VGPR demand ~150 (vs 240 in the 64-col version that spilled).
// One barrier/step; xp prefetched 2 steps ahead (2-phase A/B reg sets).
// ---------------------------------------------------------------------------
__global__ void __launch_bounds__(512, 1) rnn_mfma(
    const float* __restrict__ Whh, const float* __restrict__ bhh,
    float* __restrict__ out) {
    const int wg = blockIdx.x;      // batch group 0..3
    const int t = threadIdx.x;
    const int w = t >> 6;           // wave 0..7
    const int l = t & 63;
    const int c = l & 15;           // batch within group (N-index of D)
    const int g = l >> 4;           // k-group 0..3

    __shared__ _Float16 hls[2][16][LROW];

    // ---- one-time: W_hh A-fragments (2 m-tiles x 8 k-frags = 64 VGPR) ----
    half8 wf[2][8];
#pragma unroll
    for (int mtl = 0; mtl < 2; mtl++) {
        const float* wr = Whh + (size_t)(32 * w + 16 * mtl + c) * HDIM;
#pragma unroll
        for (int kt = 0; kt < 8; kt++) {
            float4 u = *(const float4*)&wr[32 * kt + 8 * g];
            float4 v = *(const float4*)&wr[32 * kt + 8 * g + 4];
            half8 f;
            f[0] = (_Float16)u.x; f[1] = (_Float16)u.y;
            f[2] = (_Float16)u.z; f[3] = (_Float16)u.w;
            f[4] = (_Float16)v.x; f[5] = (_Float16)v.y;
            f[6] = (_Float16)v.z; f[7] = (_Float16)v.w;
            wf[mtl][kt] = f;
        }
    }
    // bias for this lane's 8 output cols
    f32x4 bvv[2];
#pragma unroll
    for (int mtl = 0; mtl < 2; mtl++) {
        float4 bb = *(const float4*)&bhh[32 * w + 16 * mtl + 4 * g];
        bvv[mtl][0] = bb.x; bvv[mtl][1] = bb.y; bvv[mtl][2] = bb.z; bvv[mtl][3] = bb.w;
    }

    // ---- zero h_0 (both buffers) ----
    for (int i = t; i < 2 * 16 * LROW; i += 512) (&hls[0][0][0])[i] = (_Float16)0.f;

    // ---- global addressing: lane's batch row = wg*16 + c ----
    const char* ob = (const char*)out;
    uint32_t boffA = (uint32_t)((((size_t)(wg * 16 + c) * S_LEN * HDIM) + 32 * w + 4 * g) * 4u);
    uint32_t boffB = boffA + HDIM * 4;
    float* hl = out + (size_t)BATCH * S_LEN * HDIM;

    // ---- prologue: xp for s=0 / s=1 ----
    f32x4 xA[2], xB[2];
#pragma unroll
    for (int mtl = 0; mtl < 2; mtl++) {
        xA[mtl] = *(const f32x4*)(ob + boffA + mtl * 64);
        xB[mtl] = *(const f32x4*)(ob + boffB + mtl * 64);
    }

    // ---- LDS base pointers ----
    const _Float16* rdA = &hls[0][c][8 * g];
    const _Float16* rdB = &hls[1][c][8 * g];
    _Float16* wrA = &hls[1][c][32 * w + 4 * g];
    _Float16* wrB = &hls[0][c][32 * w + 4 * g];

    __syncthreads();

    auto phase = [&](int s, f32x4 (&xq)[2], uint32_t& boff,
                     const _Float16* rb, _Float16* wb) {
        // B-fragments: h rows from LDS (16B contiguous per lane)
        half8 af[8];
#pragma unroll
        for (int kt = 0; kt < 8; kt++)
            af[kt] = *(const half8*)(rb + 32 * kt);

        // seed accumulators with xp + bias
        f32x4 a[2];
#pragma unroll
        for (int mtl = 0; mtl < 2; mtl++)
            a[mtl] = xq[mtl] + bvv[mtl];

        // prefetch xp for s+2 (safe: row s+2 is overwritten only at step s+2,
        // two barriers after this read)
        if (s + 2 < S_LEN) {
#pragma unroll
            for (int mtl = 0; mtl < 2; mtl++)
                xq[mtl] = *(const f32x4*)(ob + boff + mtl * 64 + 2048);
        }

        // MFMA: A = weights (static), B = h fragments
#pragma unroll
        for (int kt = 0; kt < 8; kt++)
#pragma unroll
            for (int mtl = 0; mtl < 2; mtl++)
                a[mtl] = __builtin_amdgcn_mfma_f32_16x16x32_f16(wf[mtl][kt], af[kt], a[mtl], 0, 0, 0);

        // epilogue: tanh -> dwordx4 h_seq store + b64 LDS post
#pragma unroll
        for (int mtl = 0; mtl < 2; mtl++) {
            f32x4 v;
            v[0] = tanh_fast(a[mtl][0]);
            v[1] = tanh_fast(a[mtl][1]);
            v[2] = tanh_fast(a[mtl][2]);
            v[3] = tanh_fast(a[mtl][3]);
            *(f32x4*)(ob + boff + mtl * 64) = v;
            uint2 pk;
            pk.x = pk_f16(v[0], v[1]);
            pk.y = pk_f16(v[2], v[3]);
            *(uint2*)(wb + 16 * mtl) = pk;
            if (s == S_LEN - 1) {
                *(f32x4*)&hl[(size_t)(wg * 16 + c) * HDIM + 32 * w + 16 * mtl + 4 * g] = v;
            }
        }
        boff += 2 * HDIM * 4;
        __syncthreads();
    };

    for (int s = 0; s < S_LEN; s += 2) {
        phase(s, xA, boffA, rdA, wrA);
        phase(s + 1, xB, boffB, rdB, wrB);
    }
}

extern "C" void kernel_launch(void* const* d_in, const int* in_sizes, int n_in,
                              void* d_out, int out_size, void* d_ws, size_t ws_size,
                              hipStream_t stream) {
    const float* x   = (const float*)d_in[0];
    const float* Wxh = (const float*)d_in[1];
    const float* bxh = (const float*)d_in[2];
    const float* Whh = (const float*)d_in[3];
    const float* bhh = (const float*)d_in[4];
    float* out = (float*)d_out;

    dim3 gridA(131072 / 64, 256 / 64);  // (2048, 4)
    xp_gemm<<<gridA, 256, 0, stream>>>(x, Wxh, bxh, out);
    rnn_mfma<<<4, 512, 0, stream>>>(Whh, bhh, out);
}

// Round 9
// 2354.779 us; speedup vs baseline: 1.3173x; 1.0105x over previous
//
#include <hip/hip_runtime.h>
#include <cstdint>
#include <cstddef>

typedef _Float16 half8 __attribute__((ext_vector_type(8)));
typedef __fp16 fp16x2 __attribute__((ext_vector_type(2)));
typedef float f32x4 __attribute__((ext_vector_type(4)));

#define S_LEN 2048
#define HDIM  256
#define BATCH 64
#define LROW  264   // LDS row stride in f16 (dword stride 132 ≡ 4 mod 32)

__device__ __forceinline__ float tanh_fast(float x) {
    // tanh(x) = 1 - 2/(e^{2x}+1)
    float e = exp2f(x * 2.8853900817779268f);
    return 1.0f - 2.0f / (e + 1.0f);
}

__device__ __forceinline__ uint32_t pk_f16(float a, float b) {
#if __has_builtin(__builtin_amdgcn_cvt_pkrtz)
    fp16x2 h = __builtin_amdgcn_cvt_pkrtz(a, b);
    return __builtin_bit_cast(uint32_t, h);
#else
    union { _Float16 h[2]; uint32_t u; } v;
    v.h[0] = (_Float16)a; v.h[1] = (_Float16)b;
    return v.u;
#endif
}

// Raw workgroup barrier draining ONLY LDS (no vmcnt(0) drain!).
// __syncthreads() would force s_waitcnt vmcnt(0) before s_barrier, putting a
// full HBM round-trip (h_seq store retire + xp prefetch completion) on every
// step's critical path. Here: LDS writes made visible (lgkmcnt(0)), barrier,
// and sched_barrier fences so the compiler can't hoist next-phase ds_reads
// above the barrier or sink this phase's ds_writes below the waitcnt.
__device__ __forceinline__ void lds_barrier() {
    __builtin_amdgcn_sched_barrier(0);
    asm volatile("s_waitcnt lgkmcnt(0)" ::: "memory");
    __builtin_amdgcn_sched_barrier(0);
    __builtin_amdgcn_s_barrier();
    __builtin_amdgcn_sched_barrier(0);
}

// ---------------------------------------------------------------------------
// Kernel A: xp[m, h] = sum_i x[m, i] * Wxh[h, i] + bxh[h]   (unchanged)
// ---------------------------------------------------------------------------
__global__ void __launch_bounds__(256) xp_gemm(
    const float* __restrict__ x, const float* __restrict__ Wxh,
    const float* __restrict__ bxh, float* __restrict__ out) {
    __shared__ float As[32][68];
    __shared__ float Bs[32][68];

    const int tid = threadIdx.x;
    const int tx = tid & 15;
    const int ty = tid >> 4;
    const size_t m0 = (size_t)blockIdx.x * 64;
    const int n0 = blockIdx.y * 64;

    const int r = tid >> 3;
    const int c = (tid & 7) * 4;

    float bj[4];
#pragma unroll
    for (int j = 0; j < 4; j++) bj[j] = bxh[n0 + tx * 4 + j];

    float acc[4][4] = {};

    for (int k0 = 0; k0 < 256; k0 += 32) {
        float4 a0 = *(const float4*)&x[(m0 + r) * 256 + k0 + c];
        float4 a1 = *(const float4*)&x[(m0 + r + 32) * 256 + k0 + c];
        float4 b0 = *(const float4*)&Wxh[(size_t)(n0 + r) * 256 + k0 + c];
        float4 b1 = *(const float4*)&Wxh[(size_t)(n0 + r + 32) * 256 + k0 + c];

        __syncthreads();
        As[c + 0][r] = a0.x; As[c + 1][r] = a0.y; As[c + 2][r] = a0.z; As[c + 3][r] = a0.w;
        As[c + 0][r + 32] = a1.x; As[c + 1][r + 32] = a1.y; As[c + 2][r + 32] = a1.z; As[c + 3][r + 32] = a1.w;
        Bs[c + 0][r] = b0.x; Bs[c + 1][r] = b0.y; Bs[c + 2][r] = b0.z; Bs[c + 3][r] = b0.w;
        Bs[c + 0][r + 32] = b1.x; Bs[c + 1][r + 32] = b1.y; Bs[c + 2][r + 32] = b1.z; Bs[c + 3][r + 32] = b1.w;
        __syncthreads();

#pragma unroll
        for (int kk = 0; kk < 32; kk++) {
            float4 av = *(const float4*)&As[kk][ty * 4];
            float4 bv = *(const float4*)&Bs[kk][tx * 4];
            float aa[4] = {av.x, av.y, av.z, av.w};
            float bb[4] = {bv.x, bv.y, bv.z, bv.w};
#pragma unroll
            for (int i = 0; i < 4; i++)
#pragma unroll
                for (int j = 0; j < 4; j++)
                    acc[i][j] = fmaf(aa[i], bb[j], acc[i][j]);
        }
    }

#pragma unroll
    for (int i = 0; i < 4; i++) {
        float4 o;
        o.x = acc[i][0] + bj[0];
        o.y = acc[i][1] + bj[1];
        o.z = acc[i][2] + bj[2];
        o.w = acc[i][3] + bj[3];
        *(float4*)&out[(m0 + ty * 4 + i) * 256 + n0 + tx * 4] = o;
    }
}

// ---------------------------------------------------------------------------
// Kernel B: MFMA recurrence (R8 structure) + LDS-only barrier.
// 4 WGs x 512 threads = 8 waves (2/SIMD). Wave w owns h-cols [32w, 32w+32).
//   A (static, AGPR/VGPR): wf[mtl][kt] elem j = Whh[32w+16mtl+c][32kt+8g+j]
//   B (LDS): af[kt] elem j = h[batch c][32kt+8g+j]  (conflict-free b128)
//   D: lane (c,g) reg r = h_next[batch c][32w+16mtl+4g+r] -> dwordx4 I/O.
// xp prefetched 2 steps ahead; with the lds_barrier the prefetch slack is
// real (no vmcnt(0) drain per step).
// ---------------------------------------------------------------------------
__global__ void __launch_bounds__(512, 1) rnn_mfma(
    const float* __restrict__ Whh, const float* __restrict__ bhh,
    float* __restrict__ out) {
    const int wg = blockIdx.x;      // batch group 0..3
    const int t = threadIdx.x;
    const int w = t >> 6;           // wave 0..7
    const int l = t & 63;
    const int c = l & 15;           // batch within group (N-index of D)
    const int g = l >> 4;           // k-group 0..3

    __shared__ _Float16 hls[2][16][LROW];

    // ---- one-time: W_hh A-fragments (2 m-tiles x 8 k-frags) ----
    half8 wf[2][8];
#pragma unroll
    for (int mtl = 0; mtl < 2; mtl++) {
        const float* wr = Whh + (size_t)(32 * w + 16 * mtl + c) * HDIM;
#pragma unroll
        for (int kt = 0; kt < 8; kt++) {
            float4 u = *(const float4*)&wr[32 * kt + 8 * g];
            float4 v = *(const float4*)&wr[32 * kt + 8 * g + 4];
            half8 f;
            f[0] = (_Float16)u.x; f[1] = (_Float16)u.y;
            f[2] = (_Float16)u.z; f[3] = (_Float16)u.w;
            f[4] = (_Float16)v.x; f[5] = (_Float16)v.y;
            f[6] = (_Float16)v.z; f[7] = (_Float16)v.w;
            wf[mtl][kt] = f;
        }
    }
    // bias for this lane's 8 output cols
    f32x4 bvv[2];
#pragma unroll
    for (int mtl = 0; mtl < 2; mtl++) {
        float4 bb = *(const float4*)&bhh[32 * w + 16 * mtl + 4 * g];
        bvv[mtl][0] = bb.x; bvv[mtl][1] = bb.y; bvv[mtl][2] = bb.z; bvv[mtl][3] = bb.w;
    }

    // ---- zero h_0 (both buffers) ----
    for (int i = t; i < 2 * 16 * LROW; i += 512) (&hls[0][0][0])[i] = (_Float16)0.f;

    // ---- global addressing: lane's batch row = wg*16 + c ----
    const char* ob = (const char*)out;
    uint32_t boffA = (uint32_t)((((size_t)(wg * 16 + c) * S_LEN * HDIM) + 32 * w + 4 * g) * 4u);
    uint32_t boffB = boffA + HDIM * 4;
    float* hl = out + (size_t)BATCH * S_LEN * HDIM;

    // ---- prologue: xp for s=0 / s=1 ----
    f32x4 xA[2], xB[2];
#pragma unroll
    for (int mtl = 0; mtl < 2; mtl++) {
        xA[mtl] = *(const f32x4*)(ob + boffA + mtl * 64);
        xB[mtl] = *(const f32x4*)(ob + boffB + mtl * 64);
    }

    // ---- LDS base pointers ----
    const _Float16* rdA = &hls[0][c][8 * g];
    const _Float16* rdB = &hls[1][c][8 * g];
    _Float16* wrA = &hls[1][c][32 * w + 4 * g];
    _Float16* wrB = &hls[0][c][32 * w + 4 * g];

    __syncthreads();  // one-time full barrier (zeroing + prologue)

    auto phase = [&](int s, f32x4 (&xq)[2], uint32_t& boff,
                     const _Float16* rb, _Float16* wb) {
        // B-fragments: h rows from LDS (16B contiguous per lane)
        half8 af[8];
#pragma unroll
        for (int kt = 0; kt < 8; kt++)
            af[kt] = *(const half8*)(rb + 32 * kt);

        // seed accumulators with xp + bias
        f32x4 a[2];
#pragma unroll
        for (int mtl = 0; mtl < 2; mtl++)
            a[mtl] = xq[mtl] + bvv[mtl];

        // prefetch xp for s+2 (consumed 2 phases later via counted vmcnt wait;
        // same-lane load retires before the same-address store is issued)
        if (s + 2 < S_LEN) {
#pragma unroll
            for (int mtl = 0; mtl < 2; mtl++)
                xq[mtl] = *(const f32x4*)(ob + boff + mtl * 64 + 2048);
        }

        // MFMA: A = weights (static), B = h fragments
#pragma unroll
        for (int kt = 0; kt < 8; kt++)
#pragma unroll
            for (int mtl = 0; mtl < 2; mtl++)
                a[mtl] = __builtin_amdgcn_mfma_f32_16x16x32_f16(wf[mtl][kt], af[kt], a[mtl], 0, 0, 0);

        // epilogue: tanh -> dwordx4 h_seq store + b64 LDS post
#pragma unroll
        for (int mtl = 0; mtl < 2; mtl++) {
            f32x4 v;
            v[0] = tanh_fast(a[mtl][0]);
            v[1] = tanh_fast(a[mtl][1]);
            v[2] = tanh_fast(a[mtl][2]);
            v[3] = tanh_fast(a[mtl][3]);
            *(f32x4*)(ob + boff + mtl * 64) = v;
            uint2 pk;
            pk.x = pk_f16(v[0], v[1]);
            pk.y = pk_f16(v[2], v[3]);
            *(uint2*)(wb + 16 * mtl) = pk;
            if (s == S_LEN - 1) {
                *(f32x4*)&hl[(size_t)(wg * 16 + c) * HDIM + 32 * w + 16 * mtl + 4 * g] = v;
            }
        }
        boff += 2 * HDIM * 4;
        lds_barrier();  // LDS-only drain: h_seq stores & xp prefetches stay in flight
    };

    for (int s = 0; s < S_LEN; s += 2) {
        phase(s, xA, boffA, rdA, wrA);
        phase(s + 1, xB, boffB, rdB, wrB);
    }
}

extern "C" void kernel_launch(void* const* d_in, const int* in_sizes, int n_in,
                              void* d_out, int out_size, void* d_ws, size_t ws_size,
                              hipStream_t stream) {
    const float* x   = (const float*)d_in[0];
    const float* Wxh = (const float*)d_in[1];
    const float* bxh = (const float*)d_in[2];
    const float* Whh = (const float*)d_in[3];
    const float* bhh = (const float*)d_in[4];
    float* out = (float*)d_out;

    dim3 gridA(131072 / 64, 256 / 64);  // (2048, 4)
    xp_gemm<<<gridA, 256, 0, stream>>>(x, Wxh, bxh, out);
    rnn_mfma<<<4, 512, 0, stream>>>(Whh, bhh, out);
}

// Round 10
// 2254.553 us; speedup vs baseline: 1.3758x; 1.0445x over previous
//
#include <hip/hip_runtime.h>
#include <cstdint>
#include <cstddef>

typedef _Float16 half8 __attribute__((ext_vector_type(8)));
typedef __fp16 fp16x2 __attribute__((ext_vector_type(2)));
typedef float f32x4 __attribute__((ext_vector_type(4)));

#define S_LEN 2048
#define HDIM  256
#define BATCH 64
#define LROW  264   // LDS row stride in f16 (dword stride 132 ≡ 4 mod 32)

// tanh(x) = 1 - 2/(e^{2x}+1) with RAW hardware ops. Without -ffast-math,
// exp2f() -> __ocml_exp2_f32 (edge-case handling) and the f32 division ->
// full IEEE div_scale/div_fmas/div_fixup sequence: ~20 extra VALU instrs
// per call, x8 calls/lane/step = the VALU-issue bottleneck measured in R8/R9.
// v_exp_f32 + v_rcp_f32 + fma is 3 instructions; limits are exact at +/-inf.
__device__ __forceinline__ float tanh_fast(float x) {
#if __has_builtin(__builtin_amdgcn_exp2f) && __has_builtin(__builtin_amdgcn_rcpf)
    float e = __builtin_amdgcn_exp2f(x * 2.8853900817779268f);
    float r = __builtin_amdgcn_rcpf(e + 1.0f);
    return fmaf(-2.0f, r, 1.0f);
#else
    float e = exp2f(x * 2.8853900817779268f);
    return 1.0f - 2.0f / (e + 1.0f);
#endif
}

__device__ __forceinline__ uint32_t pk_f16(float a, float b) {
#if __has_builtin(__builtin_amdgcn_cvt_pkrtz)
    fp16x2 h = __builtin_amdgcn_cvt_pkrtz(a, b);
    return __builtin_bit_cast(uint32_t, h);
#else
    union { _Float16 h[2]; uint32_t u; } v;
    v.h[0] = (_Float16)a; v.h[1] = (_Float16)b;
    return v.u;
#endif
}

// Raw workgroup barrier draining ONLY LDS (no vmcnt(0) drain).
__device__ __forceinline__ void lds_barrier() {
    __builtin_amdgcn_sched_barrier(0);
    asm volatile("s_waitcnt lgkmcnt(0)" ::: "memory");
    __builtin_amdgcn_sched_barrier(0);
    __builtin_amdgcn_s_barrier();
    __builtin_amdgcn_sched_barrier(0);
}

// ---------------------------------------------------------------------------
// Kernel A: xp[m, h] = sum_i x[m, i] * Wxh[h, i] + bxh[h]   (unchanged)
// ---------------------------------------------------------------------------
__global__ void __launch_bounds__(256) xp_gemm(
    const float* __restrict__ x, const float* __restrict__ Wxh,
    const float* __restrict__ bxh, float* __restrict__ out) {
    __shared__ float As[32][68];
    __shared__ float Bs[32][68];

    const int tid = threadIdx.x;
    const int tx = tid & 15;
    const int ty = tid >> 4;
    const size_t m0 = (size_t)blockIdx.x * 64;
    const int n0 = blockIdx.y * 64;

    const int r = tid >> 3;
    const int c = (tid & 7) * 4;

    float bj[4];
#pragma unroll
    for (int j = 0; j < 4; j++) bj[j] = bxh[n0 + tx * 4 + j];

    float acc[4][4] = {};

    for (int k0 = 0; k0 < 256; k0 += 32) {
        float4 a0 = *(const float4*)&x[(m0 + r) * 256 + k0 + c];
        float4 a1 = *(const float4*)&x[(m0 + r + 32) * 256 + k0 + c];
        float4 b0 = *(const float4*)&Wxh[(size_t)(n0 + r) * 256 + k0 + c];
        float4 b1 = *(const float4*)&Wxh[(size_t)(n0 + r + 32) * 256 + k0 + c];

        __syncthreads();
        As[c + 0][r] = a0.x; As[c + 1][r] = a0.y; As[c + 2][r] = a0.z; As[c + 3][r] = a0.w;
        As[c + 0][r + 32] = a1.x; As[c + 1][r + 32] = a1.y; As[c + 2][r + 32] = a1.z; As[c + 3][r + 32] = a1.w;
        Bs[c + 0][r] = b0.x; Bs[c + 1][r] = b0.y; Bs[c + 2][r] = b0.z; Bs[c + 3][r] = b0.w;
        Bs[c + 0][r + 32] = b1.x; Bs[c + 1][r + 32] = b1.y; Bs[c + 2][r + 32] = b1.z; Bs[c + 3][r + 32] = b1.w;
        __syncthreads();

#pragma unroll
        for (int kk = 0; kk < 32; kk++) {
            float4 av = *(const float4*)&As[kk][ty * 4];
            float4 bv = *(const float4*)&Bs[kk][tx * 4];
            float aa[4] = {av.x, av.y, av.z, av.w};
            float bb[4] = {bv.x, bv.y, bv.z, bv.w};
#pragma unroll
            for (int i = 0; i < 4; i++)
#pragma unroll
                for (int j = 0; j < 4; j++)
                    acc[i][j] = fmaf(aa[i], bb[j], acc[i][j]);
        }
    }

#pragma unroll
    for (int i = 0; i < 4; i++) {
        float4 o;
        o.x = acc[i][0] + bj[0];
        o.y = acc[i][1] + bj[1];
        o.z = acc[i][2] + bj[2];
        o.w = acc[i][3] + bj[3];
        *(float4*)&out[(m0 + ty * 4 + i) * 256 + n0 + tx * 4] = o;
    }
}

// ---------------------------------------------------------------------------
// Kernel B: MFMA recurrence (R8/R9 structure, raw-builtin tanh).
// 4 WGs x 512 threads = 8 waves (2/SIMD). Wave w owns h-cols [32w, 32w+32).
// ---------------------------------------------------------------------------
__global__ void __launch_bounds__(512, 1) rnn_mfma(
    const float* __restrict__ Whh, const float* __restrict__ bhh,
    float* __restrict__ out) {
    const int wg = blockIdx.x;      // batch group 0..3
    const int t = threadIdx.x;
    const int w = t >> 6;           // wave 0..7
    const int l = t & 63;
    const int c = l & 15;           // batch within group (N-index of D)
    const int g = l >> 4;           // k-group 0..3

    __shared__ _Float16 hls[2][16][LROW];

    // ---- one-time: W_hh A-fragments (2 m-tiles x 8 k-frags) ----
    half8 wf[2][8];
#pragma unroll
    for (int mtl = 0; mtl < 2; mtl++) {
        const float* wr = Whh + (size_t)(32 * w + 16 * mtl + c) * HDIM;
#pragma unroll
        for (int kt = 0; kt < 8; kt++) {
            float4 u = *(const float4*)&wr[32 * kt + 8 * g];
            float4 v = *(const float4*)&wr[32 * kt + 8 * g + 4];
            half8 f;
            f[0] = (_Float16)u.x; f[1] = (_Float16)u.y;
            f[2] = (_Float16)u.z; f[3] = (_Float16)u.w;
            f[4] = (_Float16)v.x; f[5] = (_Float16)v.y;
            f[6] = (_Float16)v.z; f[7] = (_Float16)v.w;
            wf[mtl][kt] = f;
        }
    }
    // bias for this lane's 8 output cols
    f32x4 bvv[2];
#pragma unroll
    for (int mtl = 0; mtl < 2; mtl++) {
        float4 bb = *(const float4*)&bhh[32 * w + 16 * mtl + 4 * g];
        bvv[mtl][0] = bb.x; bvv[mtl][1] = bb.y; bvv[mtl][2] = bb.z; bvv[mtl][3] = bb.w;
    }

    // ---- zero h_0 (both buffers) ----
    for (int i = t; i < 2 * 16 * LROW; i += 512) (&hls[0][0][0])[i] = (_Float16)0.f;

    // ---- global addressing: lane's batch row = wg*16 + c ----
    const char* ob = (const char*)out;
    uint32_t boffA = (uint32_t)((((size_t)(wg * 16 + c) * S_LEN * HDIM) + 32 * w + 4 * g) * 4u);
    uint32_t boffB = boffA + HDIM * 4;
    float* hl = out + (size_t)BATCH * S_LEN * HDIM;

    // ---- prologue: xp for s=0 / s=1 ----
    f32x4 xA[2], xB[2];
#pragma unroll
    for (int mtl = 0; mtl < 2; mtl++) {
        xA[mtl] = *(const f32x4*)(ob + boffA + mtl * 64);
        xB[mtl] = *(const f32x4*)(ob + boffB + mtl * 64);
    }

    // ---- LDS base pointers ----
    const _Float16* rdA = &hls[0][c][8 * g];
    const _Float16* rdB = &hls[1][c][8 * g];
    _Float16* wrA = &hls[1][c][32 * w + 4 * g];
    _Float16* wrB = &hls[0][c][32 * w + 4 * g];

    __syncthreads();  // one-time full barrier (zeroing + prologue)

    auto phase = [&](int s, f32x4 (&xq)[2], uint32_t& boff,
                     const _Float16* rb, _Float16* wb) {
        // B-fragments: h rows from LDS (16B contiguous per lane)
        half8 af[8];
#pragma unroll
        for (int kt = 0; kt < 8; kt++)
            af[kt] = *(const half8*)(rb + 32 * kt);

        // seed accumulators with xp + bias
        f32x4 a[2];
#pragma unroll
        for (int mtl = 0; mtl < 2; mtl++)
            a[mtl] = xq[mtl] + bvv[mtl];

        // prefetch xp for s+2
        if (s + 2 < S_LEN) {
#pragma unroll
            for (int mtl = 0; mtl < 2; mtl++)
                xq[mtl] = *(const f32x4*)(ob + boff + mtl * 64 + 2048);
        }

        // MFMA: A = weights (static), B = h fragments
#pragma unroll
        for (int kt = 0; kt < 8; kt++)
#pragma unroll
            for (int mtl = 0; mtl < 2; mtl++)
                a[mtl] = __builtin_amdgcn_mfma_f32_16x16x32_f16(wf[mtl][kt], af[kt], a[mtl], 0, 0, 0);

        // epilogue: tanh -> dwordx4 h_seq store + b64 LDS post
#pragma unroll
        for (int mtl = 0; mtl < 2; mtl++) {
            f32x4 v;
            v[0] = tanh_fast(a[mtl][0]);
            v[1] = tanh_fast(a[mtl][1]);
            v[2] = tanh_fast(a[mtl][2]);
            v[3] = tanh_fast(a[mtl][3]);
            *(f32x4*)(ob + boff + mtl * 64) = v;
            uint2 pk;
            pk.x = pk_f16(v[0], v[1]);
            pk.y = pk_f16(v[2], v[3]);
            *(uint2*)(wb + 16 * mtl) = pk;
            if (s == S_LEN - 1) {
                *(f32x4*)&hl[(size_t)(wg * 16 + c) * HDIM + 32 * w + 16 * mtl + 4 * g] = v;
            }
        }
        boff += 2 * HDIM * 4;
        lds_barrier();
    };

    for (int s = 0; s < S_LEN; s += 2) {
        phase(s, xA, boffA, rdA, wrA);
        phase(s + 1, xB, boffB, rdB, wrB);
    }
}

extern "C" void kernel_launch(void* const* d_in, const int* in_sizes, int n_in,
                              void* d_out, int out_size, void* d_ws, size_t ws_size,
                              hipStream_t stream) {
    const float* x   = (const float*)d_in[0];
    const float* Wxh = (const float*)d_in[1];
    const float* bxh = (const float*)d_in[2];
    const float* Whh = (const float*)d_in[3];
    const float* bhh = (const float*)d_in[4];
    float* out = (float*)d_out;

    dim3 gridA(131072 / 64, 256 / 64);  // (2048, 4)
    xp_gemm<<<gridA, 256, 0, stream>>>(x, Wxh, bxh, out);
    rnn_mfma<<<4, 512, 0, stream>>>(Whh, bhh, out);
}